// Round 3
// baseline (34643.304 us; speedup 1.0000x reference)
//
#include <hip/hip_runtime.h>
#include <stdint.h>

#define HH 256
#define BB 64
#define TT 1024
#define G4H 1024
#define NSL 16       // workgroups per direction (gate-split)
#define KC 16        // h-columns owned per WG
#define SPIN_LIM (1 << 22)  // cumulative spin budget (~0.5 s) -> deadlock = fast wrong answer

typedef _Float16 v8h __attribute__((ext_vector_type(8)));
typedef float v4f __attribute__((ext_vector_type(4)));

union HFP8 { _Float16 h[8]; v8h v; };

__device__ __forceinline__ float fsig(float x) {
  float e = __builtin_amdgcn_exp2f(x * -1.44269504f);
  return __builtin_amdgcn_rcpf(1.f + e);
}
__device__ __forceinline__ float ftanh(float x) {
  float e = __builtin_amdgcn_exp2f(x * 2.88539008f);
  return 1.f - 2.f * __builtin_amdgcn_rcpf(e + 1.f);
}

// ---------------- prep kernels ----------------
__global__ void prep_w1(const float* __restrict__ w, _Float16* __restrict__ wh) {
  int i = blockIdx.x * 256 + threadIdx.x;
  if (i < 2 * 1024 * 512) wh[i] = (_Float16)w[i];
}

// xpad[d][t][b][32] fp16 : x (or reversed x) padded to K=32
__global__ void prep_x(const float* __restrict__ x, const int* __restrict__ lengths,
                       _Float16* __restrict__ xpad) {
  int i = blockIdx.x * 256 + threadIdx.x;
  if (i >= 2 * TT * BB * 32) return;
  int k = i & 31, bb = (i >> 5) & 63, t = (i >> 11) & 1023, d = (i >> 21) & 1;
  float v = 0.f;
  if (k < 3) {
    int L = lengths[bb];
    int rt = (d == 0) ? t : ((t < L) ? (L - 1 - t) : t);
    v = x[((size_t)bb * TT + rt) * 3 + k];
  }
  xpad[i] = (_Float16)v;
}

// ---------------- persistent gate-split LSTM scan ----------------
// grid 128; active blocks: (blk&7)<2 -> dir d = blk&7, slice g = blk>>3 (0..15).
// WG owns h-cols [g*16,g*16+16) -> gate rows {nt*256 + g*16 + l15}.
// W_hh (and, for layer 1, its W_ih_l1 slice) live in registers/AGPRs as MFMA
// B-fragments. h exchanged per step via parity-double-buffered global fp16
// buffer + per-t release/acquire counters (skew <= 1 by construction).
// Layer 1 computes its gate-inits itself (h1 @ W_ih1^T) BEFORE the flag wait.
template <int LAYER>
__global__ __launch_bounds__(256, 1)
void lstm_scan(const float* __restrict__ Whh, const float* __restrict__ Wih0,
               const float* __restrict__ bih, const float* __restrict__ bhh,
               const _Float16* __restrict__ xpad, const _Float16* __restrict__ h1in,
               const _Float16* __restrict__ w1h,
               _Float16* __restrict__ h1out, float* __restrict__ feat,
               _Float16* __restrict__ h_ex, int* __restrict__ flags,
               const int* __restrict__ lengths) {
  const int blk = blockIdx.x;
  if ((blk & 7) >= 2) return;
  const int d = blk & 7;
  const int g = blk >> 3;
  const int tid = threadIdx.x;
  const int w = tid >> 6;        // wave id = batch tile
  const int l = tid & 63;
  const int l15 = l & 15;
  const int hp = l >> 4;
  const int col = g * KC + l15;  // owned h-column

  __shared__ __align__(16) unsigned char lds[64 * 576];  // h(64x256 fp16, swizzled) + x(64x32 fp16)
  __shared__ int s_ok;

  // persistent W_hh fragments (MFMA B-operand layout: lane = W[j=..l15][k=kt*32+hp*8+e])
  v8h wfrag[8][4];
#pragma unroll
  for (int kt = 0; kt < 8; ++kt) {
#pragma unroll
    for (int nt = 0; nt < 4; ++nt) {
      const int j = nt * HH + col;
      const float* src = Whh + ((size_t)d * G4H + j) * HH + kt * 32 + hp * 8;
      HFP8 p;
#pragma unroll
      for (int e = 0; e < 8; ++e) p.h[e] = (_Float16)src[e];
      wfrag[kt][nt] = p.v;
    }
  }
  float bias[4];
#pragma unroll
  for (int nt = 0; nt < 4; ++nt)
    bias[nt] = bih[d * G4H + nt * HH + col] + bhh[d * G4H + nt * HH + col];

  v8h xfrag[4];     // layer 0 only
  if (LAYER == 0) {
#pragma unroll
    for (int nt = 0; nt < 4; ++nt) {
      const int j = nt * HH + col;
      HFP8 p;
#pragma unroll
      for (int e = 0; e < 8; ++e) {
        const int kl = hp * 8 + e;
        p.h[e] = (kl < 3) ? (_Float16)Wih0[((size_t)d * G4H + j) * 3 + kl] : (_Float16)0.f;
      }
      xfrag[nt] = p.v;
    }
  }
  v8h w1frag[16][4];  // layer 1 only: W_ih_l1 slice, B-operand fragments (K=512)
  if (LAYER == 1) {
#pragma unroll
    for (int kt = 0; kt < 16; ++kt)
#pragma unroll
      for (int nt = 0; nt < 4; ++nt)
        w1frag[kt][nt] =
            *(const v8h*)(w1h + ((size_t)d * G4H + nt * HH + col) * 512 + kt * 32 + hp * 8);
  }

  int Lr[4];
#pragma unroll
  for (int r = 0; r < 4; ++r) Lr[r] = lengths[w * 16 + hp * 4 + r];
  const int La = lengths[w * 16 + l15];  // length for this lane's A-row (layer 1)

  float c_reg[4] = {0.f, 0.f, 0.f, 0.f};
  float h_reg[4] = {0.f, 0.f, 0.f, 0.f};

  _Float16* hex_d = h_ex + (size_t)d * 2 * BB * HH;
  int* flg = flags + d * TT;
  int guard = 0;

  for (int t = 0; t < TT; ++t) {
    v4f acc[4];
#pragma unroll
    for (int nt = 0; nt < 4; ++nt) acc[nt] = v4f{bias[nt], bias[nt], bias[nt], bias[nt]};

    if (LAYER == 0) {  // stage x tile into LDS cols 512.. (read after barrier)
      const int row = tid >> 2, c = tid & 3;
      *(uint4*)(lds + row * 576 + 512 + c * 16) =
          *(const uint4*)(xpad + (((size_t)d * TT + t) * BB + row) * 32 + c * 8);
    } else {
      // gate-init = h1r @ W_ih1^T : independent of recurrence -> before flag wait
      const int rta = (d == 0) ? t : ((t < La) ? (La - 1 - t) : t);
      const _Float16* arow = h1in + ((size_t)(w * 16 + l15) * TT + rta) * 512;
#pragma unroll
      for (int kt = 0; kt < 16; ++kt) {
        const v8h a = *(const v8h*)(arow + kt * 32 + hp * 8);
#pragma unroll
        for (int nt = 0; nt < 4; ++nt)
          acc[nt] = __builtin_amdgcn_mfma_f32_16x16x32_f16(a, w1frag[kt][nt], acc[nt], 0, 0, 0);
      }
    }

    if (t > 0) {
      if (tid == 0) {  // single-thread arbitrated wait, uniform via LDS
        int ok = 1;
        while (__hip_atomic_load(&flg[t - 1], __ATOMIC_ACQUIRE, __HIP_MEMORY_SCOPE_AGENT) < NSL) {
          __builtin_amdgcn_s_sleep(1);
          if (++guard > SPIN_LIM) { ok = 0; break; }
        }
        s_ok = ok;
      }
      __syncthreads();
      if (!s_ok) break;  // watchdog: deadlock -> wrong answer, never a hang
      const _Float16* src = hex_d + ((t - 1) & 1) * BB * HH;
#pragma unroll
      for (int it = 0; it < 8; ++it) {
        const int q = it * 256 + tid;
        const int row = q >> 5, cc = q & 31;
        *(uint4*)(lds + row * 576 + ((cc ^ (row & 7)) * 16)) =
            *(const uint4*)(src + row * HH + cc * 8);
      }
    }
    __syncthreads();

    if (LAYER == 0) {
      const v8h a = *(const v8h*)(lds + (w * 16 + l15) * 576 + 512 + hp * 16);
#pragma unroll
      for (int nt = 0; nt < 4; ++nt)
        acc[nt] = __builtin_amdgcn_mfma_f32_16x16x32_f16(a, xfrag[nt], acc[nt], 0, 0, 0);
    }
    if (t > 0) {  // recurrence: h(t-1) @ W_hh^T
      const int row = w * 16 + l15;
#pragma unroll
      for (int kt = 0; kt < 8; ++kt) {
        const v8h a = *(const v8h*)(lds + row * 576 + (((kt * 4 + hp) ^ (row & 7)) * 16));
#pragma unroll
        for (int nt = 0; nt < 4; ++nt)
          acc[nt] = __builtin_amdgcn_mfma_f32_16x16x32_f16(a, wfrag[kt][nt], acc[nt], 0, 0, 0);
      }
    }

    _Float16* dst = hex_d + (t & 1) * BB * HH;
#pragma unroll
    for (int r = 0; r < 4; ++r) {
      const int m = w * 16 + hp * 4 + r;
      const float iv = acc[0][r], fv = acc[1][r], gv = acc[2][r], ov = acc[3][r];
      const float cn = fsig(fv) * c_reg[r] + fsig(iv) * ftanh(gv);
      const float hn = fsig(ov) * ftanh(cn);
      const bool valid = t < Lr[r];
      if (valid) { c_reg[r] = cn; h_reg[r] = hn; }
      dst[m * HH + col] = (_Float16)h_reg[r];  // carry (frozen past L)
      if (LAYER == 0) {
        const int tout = (d == 0) ? t : (valid ? (Lr[r] - 1 - t) : t);
        h1out[((size_t)m * TT + tout) * 512 + d * HH + col] =
            valid ? (_Float16)h_reg[r] : (_Float16)0.f;
      } else if (d == 1 && t == 0) {
        feat[m * 512 + HH + col] = h_reg[r];  // bwd out at orig t=L-1 == first bwd step
      }
    }
    __threadfence();
    __syncthreads();
    if (tid == 0)
      __hip_atomic_fetch_add(&flg[t], 1, __ATOMIC_RELEASE, __HIP_MEMORY_SCOPE_AGENT);
  }
  if (LAYER == 1 && d == 0) {  // fwd final state (frozen at t=L-1)
#pragma unroll
    for (int r = 0; r < 4; ++r) feat[(w * 16 + hp * 4 + r) * 512 + col] = h_reg[r];
  }
}

// ---------------- head ----------------
__global__ void head_fc1(const float* __restrict__ feat, const float* __restrict__ w,
                         const float* __restrict__ b, float* __restrict__ y) {
  const int bb = blockIdx.x, o = threadIdx.x;
  __shared__ float f[512];
  f[o] = feat[bb * 512 + o];
  f[o + 256] = feat[bb * 512 + 256 + o];
  __syncthreads();
  float acc = b[o];
  const float* wr = w + (size_t)o * 512;
  for (int i = 0; i < 512; ++i) acc = fmaf(f[i], wr[i], acc);
  y[bb * 256 + o] = fmaxf(acc, 0.f);
}
__global__ void head_bn(const float* __restrict__ y, const float* __restrict__ gamma,
                        const float* __restrict__ beta, float* __restrict__ ss) {
  const int o = threadIdx.x;
  float s1 = 0.f, s2 = 0.f;
  for (int b = 0; b < 64; ++b) { const float v = y[b * 256 + o]; s1 += v; s2 += v * v; }
  const float mean = s1 * 0.015625f;
  const float var = s2 * 0.015625f - mean * mean;
  const float sc = gamma[o] * __builtin_amdgcn_rsqf(var + 1e-5f);
  ss[o] = sc;
  ss[256 + o] = beta[o] - mean * sc;
}
__global__ void head_out(const float* __restrict__ y, const float* __restrict__ ss,
                         const float* __restrict__ w, const float* __restrict__ b,
                         float* __restrict__ out) {
  const int bb = blockIdx.x, q = threadIdx.x;
  __shared__ float z[256];
  z[q] = y[bb * 256 + q] * ss[q] + ss[256 + q];
  __syncthreads();
  if (q < 196) {
    float acc = b[q];
    const float* wr = w + (size_t)q * 256;
    for (int o = 0; o < 256; ++o) acc = fmaf(z[o], wr[o], acc);
    out[bb * 196 + q] = acc;
  }
}

extern "C" void kernel_launch(void* const* d_in, const int* in_sizes, int n_in,
                              void* d_out, int out_size, void* d_ws, size_t ws_size,
                              hipStream_t stream) {
  const float* x       = (const float*)d_in[0];
  const int* lengths   = (const int*)d_in[1];
  const float* W_ih_l0 = (const float*)d_in[2];
  const float* W_hh_l0 = (const float*)d_in[3];
  const float* b_ih_l0 = (const float*)d_in[4];
  const float* b_hh_l0 = (const float*)d_in[5];
  const float* W_ih_l1 = (const float*)d_in[6];
  const float* W_hh_l1 = (const float*)d_in[7];
  const float* b_ih_l1 = (const float*)d_in[8];
  const float* b_hh_l1 = (const float*)d_in[9];
  const float* fc1_w   = (const float*)d_in[10];
  const float* fc1_b   = (const float*)d_in[11];
  const float* bn_g    = (const float*)d_in[12];
  const float* bn_b    = (const float*)d_in[13];
  const float* fco_w   = (const float*)d_in[14];
  const float* fco_b   = (const float*)d_in[15];
  float* out = (float*)d_out;

  char* ws = (char*)d_ws;
  size_t off = 0;
  auto alloc = [&](size_t sz) { char* p = ws + off; off += (sz + 255) & ~(size_t)255; return p; };
  int* flags0      = (int*)alloc(2 * TT * 4);
  int* flags1      = (int*)alloc(2 * TT * 4);
  float* feat      = (float*)alloc(BB * 512 * 4);
  float* ybuf      = (float*)alloc(BB * 256 * 4);
  float* ss        = (float*)alloc(2 * 256 * 4);
  _Float16* h_ex   = (_Float16*)alloc(2 * 2 * BB * HH * 2);
  _Float16* w1h    = (_Float16*)alloc((size_t)2 * 1024 * 512 * 2);
  _Float16* xpad   = (_Float16*)alloc((size_t)2 * TT * BB * 32 * 2);
  _Float16* h1     = (_Float16*)alloc((size_t)BB * TT * 512 * 2);
  // total ~74.3 MB

  if (off > ws_size) {  // distinct signal: NaN output instead of zeros
    hipMemsetAsync(d_out, 0xFF, (size_t)out_size * 4, stream);
    return;
  }

  hipMemsetAsync(flags0, 0, 2 * 2 * TT * 4, stream);  // flags0+flags1 contiguous

  prep_w1<<<(2 * 1024 * 512 + 255) / 256, 256, 0, stream>>>(W_ih_l1, w1h);
  prep_x<<<(2 * TT * BB * 32 + 255) / 256, 256, 0, stream>>>(x, lengths, xpad);

  lstm_scan<0><<<128, 256, 0, stream>>>(W_hh_l0, W_ih_l0, b_ih_l0, b_hh_l0, xpad, nullptr,
                                        nullptr, h1, nullptr, h_ex, flags0, lengths);
  lstm_scan<1><<<128, 256, 0, stream>>>(W_hh_l1, nullptr, b_ih_l1, b_hh_l1, nullptr, h1,
                                        w1h, nullptr, feat, h_ex, flags1, lengths);

  head_fc1<<<64, 256, 0, stream>>>(feat, fc1_w, fc1_b, ybuf);
  head_bn<<<1, 256, 0, stream>>>(ybuf, bn_g, bn_b, ss);
  head_out<<<64, 256, 0, stream>>>(ybuf, ss, fco_w, fco_b, out);
}

// Round 4
// 11069.514 us; speedup vs baseline: 3.1296x; 3.1296x over previous
//
#include <hip/hip_runtime.h>
#include <stdint.h>

#define HH 256
#define BB 64
#define TT 1024
#define G4H 1024
#define NSL 16              // workgroups per direction (gate-split)
#define KC 16               // h-columns owned per WG
#define SPIN_LIM (1 << 24)  // cumulative spin budget -> deadlock = fast wrong answer

typedef _Float16 v8h __attribute__((ext_vector_type(8)));
typedef float v4f __attribute__((ext_vector_type(4)));

union HFP8 { _Float16 h[8]; v8h v; };
union ULL2F { unsigned long long u[2]; v8h v; };

__device__ __forceinline__ float fsig(float x) {
  float e = __builtin_amdgcn_exp2f(x * -1.44269504f);
  return __builtin_amdgcn_rcpf(1.f + e);
}
__device__ __forceinline__ float ftanh(float x) {
  float e = __builtin_amdgcn_exp2f(x * 2.88539008f);
  return 1.f - 2.f * __builtin_amdgcn_rcpf(e + 1.f);
}

// ---------------- prep kernels ----------------
__global__ void prep_w1(const float* __restrict__ w, _Float16* __restrict__ wh) {
  int i = blockIdx.x * 256 + threadIdx.x;
  if (i < 2 * 1024 * 512) wh[i] = (_Float16)w[i];
}

// xpad[d][t][b][32] fp16 : x (or reversed x) padded to K=32
__global__ void prep_x(const float* __restrict__ x, const int* __restrict__ lengths,
                       _Float16* __restrict__ xpad) {
  int i = blockIdx.x * 256 + threadIdx.x;
  if (i >= 2 * TT * BB * 32) return;
  int k = i & 31, bb = (i >> 5) & 63, t = (i >> 11) & 1023, d = (i >> 21) & 1;
  float v = 0.f;
  if (k < 3) {
    int L = lengths[bb];
    int rt = (d == 0) ? t : ((t < L) ? (L - 1 - t) : t);
    v = x[((size_t)bb * TT + rt) * 3 + k];
  }
  xpad[i] = (_Float16)v;
}

// ---------------- persistent gate-split LSTM scan ----------------
// grid 128; active blocks: (blk&7)<2 -> dir d = blk&7, slice g = blk>>3 (0..15).
// WG owns h-cols [g*16,g*16+16) -> gate rows {nt*256 + g*16 + l15}.
// W_hh (and for layer 1 its W_ih_l1 slice) are register/AGPR-resident MFMA
// B-fragments. Cross-WG exchange uses ONLY relaxed agent-scope atomics
// (sc0/sc1 ops at the device coherence point): no buffer_wbl2/buffer_inv,
// no L2 invalidation storms. Ordering: stores -> s_waitcnt vmcnt(0) ->
// __syncthreads -> tid0 publishes per-WG progress word (padded 64B).
template <int LAYER>
__global__ __launch_bounds__(256, 1)
void lstm_scan(const float* __restrict__ Whh, const float* __restrict__ Wih0,
               const float* __restrict__ bih, const float* __restrict__ bhh,
               const _Float16* __restrict__ xpad, const _Float16* __restrict__ h1in,
               const _Float16* __restrict__ w1h,
               _Float16* __restrict__ h1out, float* __restrict__ feat,
               short* __restrict__ h_ex, int* __restrict__ prog,
               const int* __restrict__ lengths) {
  const int blk = blockIdx.x;
  if ((blk & 7) >= 2) return;
  const int d = blk & 7;
  const int g = blk >> 3;
  const int tid = threadIdx.x;
  const int w = tid >> 6;        // wave id = batch tile
  const int l = tid & 63;
  const int l15 = l & 15;
  const int hp = l >> 4;
  const int col = g * KC + l15;  // owned h-column

  __shared__ int s_ok;

  // persistent W_hh fragments (B-operand layout: lane = W[j=nt*256+col][k=kt*32+hp*8+e])
  v8h wfrag[8][4];
#pragma unroll
  for (int kt = 0; kt < 8; ++kt) {
#pragma unroll
    for (int nt = 0; nt < 4; ++nt) {
      const int j = nt * HH + col;
      const float* src = Whh + ((size_t)d * G4H + j) * HH + kt * 32 + hp * 8;
      HFP8 p;
#pragma unroll
      for (int e = 0; e < 8; ++e) p.h[e] = (_Float16)src[e];
      wfrag[kt][nt] = p.v;
    }
  }
  float bias[4];
#pragma unroll
  for (int nt = 0; nt < 4; ++nt)
    bias[nt] = bih[d * G4H + nt * HH + col] + bhh[d * G4H + nt * HH + col];

  v8h xfrag[4];  // layer 0: W_ih_l0 (K=3 padded to 32)
  if (LAYER == 0) {
#pragma unroll
    for (int nt = 0; nt < 4; ++nt) {
      const int j = nt * HH + col;
      HFP8 p;
#pragma unroll
      for (int e = 0; e < 8; ++e) {
        const int kl = hp * 8 + e;
        p.h[e] = (kl < 3) ? (_Float16)Wih0[((size_t)d * G4H + j) * 3 + kl] : (_Float16)0.f;
      }
      xfrag[nt] = p.v;
    }
  }
  v8h w1frag[16][4];  // layer 1: W_ih_l1 slice, B-fragments (K=512)
  if (LAYER == 1) {
#pragma unroll
    for (int kt = 0; kt < 16; ++kt)
#pragma unroll
      for (int nt = 0; nt < 4; ++nt)
        w1frag[kt][nt] =
            *(const v8h*)(w1h + ((size_t)d * G4H + nt * HH + col) * 512 + kt * 32 + hp * 8);
  }

  int Lr[4];
#pragma unroll
  for (int r = 0; r < 4; ++r) Lr[r] = lengths[w * 16 + hp * 4 + r];
  const int La = lengths[w * 16 + l15];  // this lane's A-row length (layer 1)

  float c_reg[4] = {0.f, 0.f, 0.f, 0.f};
  float h_reg[4] = {0.f, 0.f, 0.f, 0.f};

  short* hex_d = h_ex + (size_t)d * 2 * BB * HH;   // parity-double-buffered
  int* prg = prog + d * NSL * 16;                  // progress words, 64B padded
  int guard = 0;

  for (int t = 0; t < TT; ++t) {
    v4f acc[4];
#pragma unroll
    for (int nt = 0; nt < 4; ++nt) acc[nt] = v4f{bias[nt], bias[nt], bias[nt], bias[nt]};

    if (LAYER == 0) {  // x contribution: plain cached loads (read-only data)
      const v8h a = *(const v8h*)(xpad + (((size_t)d * TT + t) * BB + w * 16 + l15) * 32 + hp * 8);
#pragma unroll
      for (int nt = 0; nt < 4; ++nt)
        acc[nt] = __builtin_amdgcn_mfma_f32_16x16x32_f16(a, xfrag[nt], acc[nt], 0, 0, 0);
    } else {
      // gate-init = h1r @ W_ih1^T : independent of recurrence -> before the wait
      const int rta = (d == 0) ? t : ((t < La) ? (La - 1 - t) : t);
      const _Float16* arow = h1in + ((size_t)(w * 16 + l15) * TT + rta) * 512;
#pragma unroll
      for (int kt = 0; kt < 16; ++kt) {
        const v8h a = *(const v8h*)(arow + kt * 32 + hp * 8);
#pragma unroll
        for (int nt = 0; nt < 4; ++nt)
          acc[nt] = __builtin_amdgcn_mfma_f32_16x16x32_f16(a, w1frag[kt][nt], acc[nt], 0, 0, 0);
      }
    }

    if (t > 0) {
      if (w == 0) {  // wave 0: 16 lanes poll the 16 progress words (coalesced round)
        int ok = 1;
        for (;;) {
          int v = (l < NSL)
                      ? __hip_atomic_load(&prg[l * 16], __ATOMIC_RELAXED, __HIP_MEMORY_SCOPE_AGENT)
                      : (t - 1);
          if (__all(v >= t - 1)) break;
          __builtin_amdgcn_s_sleep(1);
          if (++guard > SPIN_LIM) { ok = 0; break; }
        }
        if (l == 0) s_ok = ok;
      }
      __syncthreads();              // publishes s_ok; others waited here during spin
      if (!s_ok) break;             // watchdog: deadlock -> fast wrong answer, no hang

      // A-fragments straight from exchange buffer: 16 x 8B relaxed-atomic loads
      const unsigned long long* src =
          (const unsigned long long*)(hex_d + ((t - 1) & 1) * BB * HH);
      const int base = (w * 16 + l15) * 64 + hp * 2;  // ull index into 256-col row
      unsigned long long fr[16];
#pragma unroll
      for (int kt = 0; kt < 8; ++kt) {
        fr[2 * kt] = __hip_atomic_load(src + base + kt * 8, __ATOMIC_RELAXED,
                                       __HIP_MEMORY_SCOPE_AGENT);
        fr[2 * kt + 1] = __hip_atomic_load(src + base + kt * 8 + 1, __ATOMIC_RELAXED,
                                           __HIP_MEMORY_SCOPE_AGENT);
      }
#pragma unroll
      for (int kt = 0; kt < 8; ++kt) {
        ULL2F u;
        u.u[0] = fr[2 * kt];
        u.u[1] = fr[2 * kt + 1];
#pragma unroll
        for (int nt = 0; nt < 4; ++nt)
          acc[nt] = __builtin_amdgcn_mfma_f32_16x16x32_f16(u.v, wfrag[kt][nt], acc[nt], 0, 0, 0);
      }
    }

    short* dst = hex_d + (t & 1) * BB * HH;
#pragma unroll
    for (int r = 0; r < 4; ++r) {
      const int m = w * 16 + hp * 4 + r;
      const float iv = acc[0][r], fv = acc[1][r], gv = acc[2][r], ov = acc[3][r];
      const float cn = fsig(fv) * c_reg[r] + fsig(iv) * ftanh(gv);
      const float hn = fsig(ov) * ftanh(cn);
      const bool valid = t < Lr[r];
      if (valid) { c_reg[r] = cn; h_reg[r] = hn; }
      union { _Float16 f; short s; } hb;
      hb.f = (_Float16)h_reg[r];
      __hip_atomic_store(&dst[m * HH + col], hb.s, __ATOMIC_RELAXED, __HIP_MEMORY_SCOPE_AGENT);
      if (LAYER == 0) {
        const int tout = (d == 0) ? t : (valid ? (Lr[r] - 1 - t) : t);
        h1out[((size_t)m * TT + tout) * 512 + d * HH + col] =
            valid ? (_Float16)h_reg[r] : (_Float16)0.f;
      } else if (d == 1 && t == 0) {
        feat[m * 512 + HH + col] = h_reg[r];  // bwd out at orig t=L-1 == first bwd step
      }
    }
    asm volatile("s_waitcnt vmcnt(0)" ::: "memory");  // my exchange stores are at L3
    __syncthreads();                                   // => all WG stores are at L3
    if (tid == 0)
      __hip_atomic_store(&prg[g * 16], t, __ATOMIC_RELAXED, __HIP_MEMORY_SCOPE_AGENT);
  }
  if (LAYER == 1 && d == 0) {  // fwd final state (frozen at t=L-1)
#pragma unroll
    for (int r = 0; r < 4; ++r) feat[(w * 16 + hp * 4 + r) * 512 + col] = h_reg[r];
  }
}

// ---------------- head ----------------
__global__ void head_fc1(const float* __restrict__ feat, const float* __restrict__ w,
                         const float* __restrict__ b, float* __restrict__ y) {
  const int bb = blockIdx.x, o = threadIdx.x;
  __shared__ float f[512];
  f[o] = feat[bb * 512 + o];
  f[o + 256] = feat[bb * 512 + 256 + o];
  __syncthreads();
  float acc = b[o];
  const float* wr = w + (size_t)o * 512;
  for (int i = 0; i < 512; ++i) acc = fmaf(f[i], wr[i], acc);
  y[bb * 256 + o] = fmaxf(acc, 0.f);
}
__global__ void head_bn(const float* __restrict__ y, const float* __restrict__ gamma,
                        const float* __restrict__ beta, float* __restrict__ ss) {
  const int o = threadIdx.x;
  float s1 = 0.f, s2 = 0.f;
  for (int b = 0; b < 64; ++b) { const float v = y[b * 256 + o]; s1 += v; s2 += v * v; }
  const float mean = s1 * 0.015625f;
  const float var = s2 * 0.015625f - mean * mean;
  const float sc = gamma[o] * __builtin_amdgcn_rsqf(var + 1e-5f);
  ss[o] = sc;
  ss[256 + o] = beta[o] - mean * sc;
}
__global__ void head_out(const float* __restrict__ y, const float* __restrict__ ss,
                         const float* __restrict__ w, const float* __restrict__ b,
                         float* __restrict__ out) {
  const int bb = blockIdx.x, q = threadIdx.x;
  __shared__ float z[256];
  z[q] = y[bb * 256 + q] * ss[q] + ss[256 + q];
  __syncthreads();
  if (q < 196) {
    float acc = b[q];
    const float* wr = w + (size_t)q * 256;
    for (int o = 0; o < 256; ++o) acc = fmaf(z[o], wr[o], acc);
    out[bb * 196 + q] = acc;
  }
}

extern "C" void kernel_launch(void* const* d_in, const int* in_sizes, int n_in,
                              void* d_out, int out_size, void* d_ws, size_t ws_size,
                              hipStream_t stream) {
  const float* x       = (const float*)d_in[0];
  const int* lengths   = (const int*)d_in[1];
  const float* W_ih_l0 = (const float*)d_in[2];
  const float* W_hh_l0 = (const float*)d_in[3];
  const float* b_ih_l0 = (const float*)d_in[4];
  const float* b_hh_l0 = (const float*)d_in[5];
  const float* W_ih_l1 = (const float*)d_in[6];
  const float* W_hh_l1 = (const float*)d_in[7];
  const float* b_ih_l1 = (const float*)d_in[8];
  const float* b_hh_l1 = (const float*)d_in[9];
  const float* fc1_w   = (const float*)d_in[10];
  const float* fc1_b   = (const float*)d_in[11];
  const float* bn_g    = (const float*)d_in[12];
  const float* bn_b    = (const float*)d_in[13];
  const float* fco_w   = (const float*)d_in[14];
  const float* fco_b   = (const float*)d_in[15];
  float* out = (float*)d_out;

  char* ws = (char*)d_ws;
  size_t off = 0;
  auto alloc = [&](size_t sz) { char* p = ws + off; off += (sz + 255) & ~(size_t)255; return p; };
  int* prog0       = (int*)alloc(2 * NSL * 16 * 4);   // per-WG progress words, 64B padded
  int* prog1       = (int*)alloc(2 * NSL * 16 * 4);
  float* feat      = (float*)alloc(BB * 512 * 4);
  float* ybuf      = (float*)alloc(BB * 256 * 4);
  float* ss        = (float*)alloc(2 * 256 * 4);
  short* h_ex      = (short*)alloc(2 * 2 * BB * HH * 2);
  _Float16* w1h    = (_Float16*)alloc((size_t)2 * 1024 * 512 * 2);
  _Float16* xpad   = (_Float16*)alloc((size_t)2 * TT * BB * 32 * 2);
  _Float16* h1     = (_Float16*)alloc((size_t)BB * TT * 512 * 2);
  // total ~74.3 MB

  if (off > ws_size) {  // distinct signal: NaN output instead of zeros
    hipMemsetAsync(d_out, 0xFF, (size_t)out_size * 4, stream);
    return;
  }

  hipMemsetAsync(prog0, 0xFF, 2 * 2 * NSL * 16 * 4, stream);  // prog = -1 (contiguous)

  prep_w1<<<(2 * 1024 * 512 + 255) / 256, 256, 0, stream>>>(W_ih_l1, w1h);
  prep_x<<<(2 * TT * BB * 32 + 255) / 256, 256, 0, stream>>>(x, lengths, xpad);

  lstm_scan<0><<<128, 256, 0, stream>>>(W_hh_l0, W_ih_l0, b_ih_l0, b_hh_l0, xpad, nullptr,
                                        nullptr, h1, nullptr, h_ex, prog0, lengths);
  lstm_scan<1><<<128, 256, 0, stream>>>(W_hh_l1, nullptr, b_ih_l1, b_hh_l1, nullptr, h1,
                                        w1h, nullptr, feat, h_ex, prog1, lengths);

  head_fc1<<<64, 256, 0, stream>>>(feat, fc1_w, fc1_b, ybuf);
  head_bn<<<1, 256, 0, stream>>>(ybuf, bn_g, bn_b, ss);
  head_out<<<64, 256, 0, stream>>>(ybuf, ss, fco_w, fco_b, out);
}